// Round 3
// baseline (479.438 us; speedup 1.0000x reference)
//
#include <hip/hip_runtime.h>
#include <hip/hip_bf16.h>

#define N0 4096
#define N1 16384
#define HID 128
#define LAT 64
#define DIM 3
#define NAUG 21
#define JTOT 512   // xl(128) | xr(128) | lins(128) | pe(128)
#define KP 132     // padded k (131 real + 1 zero row)

__device__ __constant__ int c_aug[NAUG] = {1,2,3,4,5,6,7,8,9,10,11,12,13,14,
                                           15,16,17,18,19,21,24};

// ---------------------------------------------------------------------------
// Prep: transpose/concat weights into Wt[c][k(132, padded)][j(512)],
// bias_cat[c][512], and lin0 weight transpose Wt0[k(64)][j(128)].
// ---------------------------------------------------------------------------
__global__ void prep_kernel(const float* __restrict__ Wl,
                            const float* __restrict__ Wr,
                            const float* __restrict__ We,
                            const float* __restrict__ linsW,
                            const float* __restrict__ bl,
                            const float* __restrict__ br,
                            const float* __restrict__ linsb,
                            const float* __restrict__ lin0W,
                            float* __restrict__ Wt,
                            float* __restrict__ bias_cat,
                            float* __restrict__ Wt0) {
    int tid = blockIdx.x * blockDim.x + threadIdx.x;
    const int NWT = 4 * KP * JTOT;           // 270336
    if (tid < NWT) {
        int c = tid / (KP * JTOT);
        int rem = tid - c * KP * JTOT;
        int k = rem / JTOT;
        int j = rem - k * JTOT;
        float v = 0.0f;
        if (k < 131) {
            if (j < 128)        v = Wl[(c * 128 + j) * 131 + k];
            else if (j < 256)   v = Wr[(c * 128 + (j - 128)) * 131 + k];
            else if (j < 384)   v = linsW[(c * 128 + (j - 256)) * 131 + k];
            else                v = (k >= 128) ? We[(c * 128 + (j - 384)) * 3 + (k - 128)]
                                               : 0.0f;
        }
        Wt[tid] = v;
    } else if (tid < NWT + 4 * JTOT) {       // bias_cat
        int idx = tid - NWT;
        int c = idx / JTOT;
        int j = idx - c * JTOT;
        float v;
        if (j < 128)        v = bl[c * 128 + j];
        else if (j < 256)   v = br[c * 128 + (j - 128)];
        else if (j < 384)   v = linsb[c * 128 + (j - 256)];
        else                v = 0.0f;
        bias_cat[idx] = v;
    } else if (tid < NWT + 4 * JTOT + 64 * 128) {  // Wt0
        int idx = tid - NWT - 4 * JTOT;
        int k = idx / 128;
        int j = idx - k * 128;
        Wt0[idx] = lin0W[j * 64 + k];
    }
}

// ---------------------------------------------------------------------------
// lin0: x0[n][j] = latent[n] . lin0_W[j] + b[j]   (4096x64 @ 64x128)
// ---------------------------------------------------------------------------
__global__ void lin0_kernel(const float* __restrict__ latent,
                            const float* __restrict__ Wt0,
                            const float* __restrict__ b,
                            float* __restrict__ x0) {
    __shared__ float lrow[64];
    int n = blockIdx.x;
    int j = threadIdx.x;
    if (j < 64) lrow[j] = latent[n * 64 + j];
    __syncthreads();
    float acc = b[j];
#pragma unroll 8
    for (int k = 0; k < 64; ++k) acc += lrow[k] * Wt0[k * 128 + j];
    x0[n * 128 + j] = acc;
}

// ---------------------------------------------------------------------------
// Fused per-layer GEMM (unchanged from R1 — dropped out of top-5)
// ---------------------------------------------------------------------------
#define GR 16   // rows per block
__global__ __launch_bounds__(256)
void fused_gemm_kernel(const float* __restrict__ x,
                       const float* __restrict__ pos,
                       const float* __restrict__ Wt,       // [132][512] this layer
                       const float* __restrict__ bias_cat, // [512] this layer
                       float* __restrict__ xl, float* __restrict__ xr,
                       float* __restrict__ lin, float* __restrict__ pe,
                       int N) {
    __shared__ float h[GR][KP];
    int n0 = blockIdx.x * GR;
    int tid = threadIdx.x;
    for (int idx = tid; idx < GR * KP; idx += 256) {
        int r = idx / KP;
        int k = idx - r * KP;
        float v;
        if (k < 128)      v = x[(n0 + r) * 128 + k];
        else if (k < 131) v = pos[(n0 + r) * 3 + (k - 128)];
        else              v = 0.0f;
        h[r][k] = v;
    }
    __syncthreads();

    int jg = tid & 63;
    int rg = tid >> 6;
    int j0 = jg * 8;
    int r0 = rg * 4;

    float acc[4][8];
    {
        float bv[8];
        *(float4*)&bv[0] = *(const float4*)&bias_cat[j0];
        *(float4*)&bv[4] = *(const float4*)&bias_cat[j0 + 4];
#pragma unroll
        for (int r = 0; r < 4; ++r)
#pragma unroll
            for (int c = 0; c < 8; ++c) acc[r][c] = bv[c];
    }

    for (int k = 0; k < KP; k += 4) {
        float ha[4][4];
#pragma unroll
        for (int r = 0; r < 4; ++r)
            *(float4*)&ha[r][0] = *(const float4*)&h[r0 + r][k];
        float wv[4][8];
#pragma unroll
        for (int kk = 0; kk < 4; ++kk) {
            *(float4*)&wv[kk][0] = *(const float4*)&Wt[(k + kk) * JTOT + j0];
            *(float4*)&wv[kk][4] = *(const float4*)&Wt[(k + kk) * JTOT + j0 + 4];
        }
#pragma unroll
        for (int kk = 0; kk < 4; ++kk)
#pragma unroll
            for (int r = 0; r < 4; ++r)
#pragma unroll
                for (int c = 0; c < 8; ++c)
                    acc[r][c] += ha[r][kk] * wv[kk][c];
    }

    int seg = j0 >> 7;          // 0..3
    int jj = j0 & 127;
    float* dst = (seg == 0) ? xl : (seg == 1) ? xr : (seg == 2) ? lin : pe;
#pragma unroll
    for (int r = 0; r < 4; ++r) {
        float* p = &dst[(size_t)(n0 + r0 + r) * 128 + jj];
        *(float4*)p       = make_float4(acc[r][0], acc[r][1], acc[r][2], acc[r][3]);
        *(float4*)(p + 4) = make_float4(acc[r][4], acc[r][5], acc[r][6], acc[r][7]);
    }
}

// ---------------------------------------------------------------------------
// GATv2 gather + softmax + aggregate + elu + residual. One wave per dst node.
// ---------------------------------------------------------------------------
__global__ __launch_bounds__(256)
void gat_gather_kernel(const float* __restrict__ xl, const float* __restrict__ xr,
                       const float* __restrict__ pe, const float* __restrict__ lin,
                       const float* __restrict__ att, const float* __restrict__ bias,
                       float* __restrict__ xout, int N) {
    int wave = threadIdx.x >> 6;
    int lane = threadIdx.x & 63;
    int d = blockIdx.x * 4 + wave;
    if (d >= N) return;
    int i0 = 2 * lane;

    float att0 = att[i0], att1 = att[i0 + 1];
    float2 xld = *(const float2*)&xl[d * 128 + i0];
    float2 xrd = *(const float2*)&xr[d * 128 + i0];
    float2 ped = *(const float2*)&pe[d * 128 + i0];

    float a[NAUG + 1];
    float xs0[NAUG], xs1[NAUG];
    float pes0 = 0.0f, pes1 = 0.0f;

#pragma unroll
    for (int k = 0; k < NAUG; ++k) {
        int s = d - c_aug[k];
        if (s < 0) s += N;
        float2 xls = *(const float2*)&xl[s * 128 + i0];
        float2 pes = *(const float2*)&pe[s * 128 + i0];
        xs0[k] = xls.x; xs1[k] = xls.y;
        pes0 += pes.x;  pes1 += pes.y;
        float m0 = xls.x + xrd.x + ped.x - pes.x;
        float m1 = xls.y + xrd.y + ped.y - pes.y;
        m0 = m0 > 0.0f ? m0 : 0.2f * m0;
        m1 = m1 > 0.0f ? m1 : 0.2f * m1;
        float p = att0 * m0 + att1 * m1;
#pragma unroll
        for (int off = 1; off < 64; off <<= 1) p += __shfl_xor(p, off, 64);
        a[k] = p;
    }
    {   // self loop: eattr = mean over in-edges = ped - mean(pes)
        const float inv21 = 1.0f / 21.0f;
        float m0 = xld.x + xrd.x + (ped.x - pes0 * inv21);
        float m1 = xld.y + xrd.y + (ped.y - pes1 * inv21);
        m0 = m0 > 0.0f ? m0 : 0.2f * m0;
        m1 = m1 > 0.0f ? m1 : 0.2f * m1;
        float p = att0 * m0 + att1 * m1;
#pragma unroll
        for (int off = 1; off < 64; off <<= 1) p += __shfl_xor(p, off, 64);
        a[NAUG] = p;
    }

    float amax = a[0];
#pragma unroll
    for (int k = 1; k <= NAUG; ++k) amax = fmaxf(amax, a[k]);
    float den = 0.0f;
#pragma unroll
    for (int k = 0; k <= NAUG; ++k) { a[k] = __expf(a[k] - amax); den += a[k]; }
    float inv = 1.0f / (den + 1e-16f);

    float o0 = 0.0f, o1 = 0.0f;
#pragma unroll
    for (int k = 0; k < NAUG; ++k) {
        float al = a[k] * inv;
        o0 += al * xs0[k];
        o1 += al * xs1[k];
    }
    {
        float al = a[NAUG] * inv;
        o0 += al * xld.x;
        o1 += al * xld.y;
    }
    o0 += bias[i0];
    o1 += bias[i0 + 1];
    o0 = o0 > 0.0f ? o0 : __expf(o0) - 1.0f;
    o1 = o1 > 0.0f ? o1 : __expf(o1) - 1.0f;
    float2 l2 = *(const float2*)&lin[d * 128 + i0];
    float2 res;
    res.x = o0 + l2.x;
    res.y = o1 + l2.y;
    *(float2*)&xout[d * 128 + i0] = res;
}

// ---------------------------------------------------------------------------
// knn v2: float4-padded LDS points (1 ds_read_b128/point), 4 y per thread,
// unroll-4 so reads batch under one lgkmcnt wait. 32 chunks of 128 points.
// ---------------------------------------------------------------------------
#define KCH 32
#define KCS 128   // 4096 / 32
#define YPT 4

__device__ __forceinline__ void top3_insert(float d2, int gi,
                                            float (&bd)[3], int (&bi)[3]) {
    if (d2 < bd[2]) {
        if (d2 < bd[0])      { bd[2]=bd[1]; bi[2]=bi[1]; bd[1]=bd[0]; bi[1]=bi[0]; bd[0]=d2; bi[0]=gi; }
        else if (d2 < bd[1]) { bd[2]=bd[1]; bi[2]=bi[1]; bd[1]=d2;    bi[1]=gi; }
        else                 { bd[2]=d2;    bi[2]=gi; }
    }
}

__global__ __launch_bounds__(256)
void knn_part_kernel(const float* __restrict__ pos0, const float* __restrict__ pos1,
                     float* __restrict__ pb_d, int* __restrict__ pb_i) {
    __shared__ float4 sx[KCS];
    int tid = threadIdx.x;
    int chunk = blockIdx.y;
    for (int t = tid; t < KCS; t += 256) {
        const float* p = &pos0[(chunk * KCS + t) * 3];
        sx[t] = make_float4(p[0], p[1], p[2], 0.0f);
    }
    __syncthreads();
    int ybase = blockIdx.x * (256 * YPT) + tid;
    float py[YPT][3];
#pragma unroll
    for (int u = 0; u < YPT; ++u) {
        int y = ybase + u * 256;
        py[u][0] = pos1[y * 3];
        py[u][1] = pos1[y * 3 + 1];
        py[u][2] = pos1[y * 3 + 2];
    }
    float bd[YPT][3]; int bi[YPT][3];
#pragma unroll
    for (int u = 0; u < YPT; ++u) {
        bd[u][0] = bd[u][1] = bd[u][2] = 1e30f;
        bi[u][0] = bi[u][1] = bi[u][2] = 0;
    }
    int gbase = chunk * KCS;
    for (int i = 0; i < KCS; i += 4) {
        float4 s[4];
#pragma unroll
        for (int v = 0; v < 4; ++v) s[v] = sx[i + v];
#pragma unroll
        for (int v = 0; v < 4; ++v) {
            int gi = gbase + i + v;
#pragma unroll
            for (int u = 0; u < YPT; ++u) {
                float dx = py[u][0] - s[v].x;
                float dy = py[u][1] - s[v].y;
                float dz = py[u][2] - s[v].z;
                float d2 = dx * dx + dy * dy + dz * dz;
                top3_insert(d2, gi, bd[u], bi[u]);
            }
        }
    }
#pragma unroll
    for (int u = 0; u < YPT; ++u) {
        int y = ybase + u * 256;
        int base = (chunk * N1 + y) * 3;
        pb_d[base] = bd[u][0]; pb_d[base + 1] = bd[u][1]; pb_d[base + 2] = bd[u][2];
        pb_i[base] = bi[u][0]; pb_i[base + 1] = bi[u][1]; pb_i[base + 2] = bi[u][2];
    }
}

__global__ __launch_bounds__(256)
void knn_merge_kernel(const float* __restrict__ pb_d, const int* __restrict__ pb_i,
                      int* __restrict__ knn_idx, float* __restrict__ knn_w) {
    int y = blockIdx.x * 256 + threadIdx.x;
    float bd[3] = {1e30f, 1e30f, 1e30f};
    int bi[3] = {0, 0, 0};
    for (int c = 0; c < KCH; ++c) {
        int base = (c * N1 + y) * 3;
        float d0 = pb_d[base];
        if (d0 >= bd[2]) continue;   // chunk candidates sorted ascending
        top3_insert(d0, pb_i[base], bd, bi);
        top3_insert(pb_d[base + 1], pb_i[base + 1], bd, bi);
        top3_insert(pb_d[base + 2], pb_i[base + 2], bd, bi);
    }
    knn_idx[y * 3]     = bi[0];
    knn_idx[y * 3 + 1] = bi[1];
    knn_idx[y * 3 + 2] = bi[2];
    knn_w[y * 3]     = 1.0f / fmaxf(bd[0], 1e-16f);
    knn_w[y * 3 + 1] = 1.0f / fmaxf(bd[1], 1e-16f);
    knn_w[y * 3 + 2] = 1.0f / fmaxf(bd[2], 1e-16f);
}

__global__ __launch_bounds__(256)
void interp_kernel(const float* __restrict__ x0, const int* __restrict__ knn_idx,
                   const float* __restrict__ knn_w, float* __restrict__ x1) {
    int wave = threadIdx.x >> 6;
    int lane = threadIdx.x & 63;
    int y = blockIdx.x * 4 + wave;
    int i0 = 2 * lane;
    float w0 = knn_w[y * 3], w1 = knn_w[y * 3 + 1], w2 = knn_w[y * 3 + 2];
    int j0 = knn_idx[y * 3], j1 = knn_idx[y * 3 + 1], j2 = knn_idx[y * 3 + 2];
    float inv = 1.0f / (w0 + w1 + w2);
    float2 a = *(const float2*)&x0[j0 * 128 + i0];
    float2 b = *(const float2*)&x0[j1 * 128 + i0];
    float2 c = *(const float2*)&x0[j2 * 128 + i0];
    float2 r;
    r.x = (w0 * a.x + w1 * b.x + w2 * c.x) * inv;
    r.y = (w0 * a.y + w1 * b.y + w2 * c.y) * inv;
    *(float2*)&x1[y * 128 + i0] = r;
}

// ---------------------------------------------------------------------------
// Output head: out[y] = [x1[y] | pos1[y]] @ out_W.T + out_b. One wave per y.
// ---------------------------------------------------------------------------
__global__ __launch_bounds__(256)
void out_kernel(const float* __restrict__ x1, const float* __restrict__ pos1,
                const float* __restrict__ W, const float* __restrict__ b,
                float* __restrict__ out) {
    int wave = threadIdx.x >> 6;
    int lane = threadIdx.x & 63;
    int y = blockIdx.x * 4 + wave;
    float h0 = x1[y * 128 + lane];
    float h1 = x1[y * 128 + 64 + lane];
    float acc[3];
#pragma unroll
    for (int o = 0; o < 3; ++o) {
        float p = h0 * W[o * 131 + lane] + h1 * W[o * 131 + 64 + lane];
#pragma unroll
        for (int off = 1; off < 64; off <<= 1) p += __shfl_xor(p, off, 64);
        acc[o] = p;
    }
    if (lane == 0) {
        float p0 = pos1[y * 3], p1 = pos1[y * 3 + 1], p2 = pos1[y * 3 + 2];
#pragma unroll
        for (int o = 0; o < 3; ++o) {
            out[y * 3 + o] = acc[o] + b[o] + p0 * W[o * 131 + 128]
                           + p1 * W[o * 131 + 129] + p2 * W[o * 131 + 130];
        }
    }
}

// ---------------------------------------------------------------------------
extern "C" void kernel_launch(void* const* d_in, const int* in_sizes, int n_in,
                              void* d_out, int out_size, void* d_ws, size_t ws_size,
                              hipStream_t stream) {
    (void)in_sizes; (void)n_in; (void)out_size; (void)ws_size;
    const float* latent   = (const float*)d_in[0];
    const float* pos0     = (const float*)d_in[1];
    const float* pos1     = (const float*)d_in[2];
    const float* conv_Wl  = (const float*)d_in[5];
    const float* conv_bl  = (const float*)d_in[6];
    const float* conv_Wr  = (const float*)d_in[7];
    const float* conv_br  = (const float*)d_in[8];
    const float* conv_We  = (const float*)d_in[9];
    const float* conv_att = (const float*)d_in[10];
    const float* conv_bias= (const float*)d_in[11];
    const float* lin0_W   = (const float*)d_in[12];
    const float* lin0_b   = (const float*)d_in[13];
    const float* lins_W   = (const float*)d_in[14];
    const float* lins_b   = (const float*)d_in[15];
    const float* out_W    = (const float*)d_in[16];
    const float* out_b    = (const float*)d_in[17];
    float* out = (float*)d_out;

    char* ws = (char*)d_ws;
    float* Wt       = (float*)ws;  ws += (size_t)4 * KP * JTOT * 4;
    float* bias_cat = (float*)ws;  ws += (size_t)4 * JTOT * 4;
    float* Wt0      = (float*)ws;  ws += (size_t)64 * 128 * 4;
    float* bufA     = (float*)ws;  ws += (size_t)N1 * 128 * 4;
    float* bufB     = (float*)ws;  ws += (size_t)N1 * 128 * 4;
    float* xlb      = (float*)ws;  ws += (size_t)N1 * 128 * 4;
    float* xrb      = (float*)ws;  ws += (size_t)N1 * 128 * 4;
    float* linb     = (float*)ws;  ws += (size_t)N1 * 128 * 4;
    float* peb      = (float*)ws;  ws += (size_t)N1 * 128 * 4;
    float* pb_d     = (float*)ws;  ws += (size_t)KCH * N1 * 3 * 4;
    int*   pb_i     = (int*)ws;    ws += (size_t)KCH * N1 * 3 * 4;
    int*   knn_idx  = (int*)ws;    ws += (size_t)N1 * 3 * 4;
    float* knn_w    = (float*)ws;  ws += (size_t)N1 * 3 * 4;

    prep_kernel<<<1100, 256, 0, stream>>>(conv_Wl, conv_Wr, conv_We, lins_W,
                                          conv_bl, conv_br, lins_b, lin0_W,
                                          Wt, bias_cat, Wt0);
    lin0_kernel<<<N0, 128, 0, stream>>>(latent, Wt0, lin0_b, bufA);

    float* cur = bufA; float* nxt = bufB;
    for (int c = 0; c < 2; ++c) {
        fused_gemm_kernel<<<N0 / GR, 256, 0, stream>>>(
            cur, pos0, Wt + (size_t)c * KP * JTOT, bias_cat + c * JTOT,
            xlb, xrb, linb, peb, N0);
        gat_gather_kernel<<<N0 / 4, 256, 0, stream>>>(
            xlb, xrb, peb, linb, conv_att + c * 128, conv_bias + c * 128,
            nxt, N0);
        float* t = cur; cur = nxt; nxt = t;
    }

    knn_part_kernel<<<dim3(N1 / (256 * YPT), KCH), 256, 0, stream>>>(pos0, pos1, pb_d, pb_i);
    knn_merge_kernel<<<N1 / 256, 256, 0, stream>>>(pb_d, pb_i, knn_idx, knn_w);
    interp_kernel<<<N1 / 4, 256, 0, stream>>>(cur, knn_idx, knn_w, bufB);

    cur = bufB; nxt = bufA;
    for (int c = 2; c < 4; ++c) {
        fused_gemm_kernel<<<N1 / GR, 256, 0, stream>>>(
            cur, pos1, Wt + (size_t)c * KP * JTOT, bias_cat + c * JTOT,
            xlb, xrb, linb, peb, N1);
        gat_gather_kernel<<<N1 / 4, 256, 0, stream>>>(
            xlb, xrb, peb, linb, conv_att + c * 128, conv_bias + c * 128,
            nxt, N1);
        float* t = cur; cur = nxt; nxt = t;
    }

    out_kernel<<<N1 / 4, 256, 0, stream>>>(cur, pos1, out_W, out_b, out);
}